// Round 3
// baseline (422.045 us; speedup 1.0000x reference)
//
#include <hip/hip_runtime.h>
#include <stdint.h>

#define B_ 8
#define C_ 256
#define D_ 128
#define N_ 4096

typedef __bf16 bf16x8 __attribute__((ext_vector_type(8)));
typedef uint16_t u16x8 __attribute__((ext_vector_type(8)));
typedef uint16_t u16x4 __attribute__((ext_vector_type(4)));
typedef float f32x4 __attribute__((ext_vector_type(4)));
typedef float f32x16 __attribute__((ext_vector_type(16)));
typedef uint32_t u32x4 __attribute__((ext_vector_type(4)));
typedef unsigned int uiv2 __attribute__((ext_vector_type(2)));

__device__ inline uint16_t f2bf(float x) {
    union { float f; uint32_t u; } v; v.f = x;
    uint32_t u = v.u;
    return (uint16_t)((u + 0x7FFFu + ((u >> 16) & 1u)) >> 16);
}

// pack two floats -> two bf16 in one u32 (low = lo, high = hi); compiler emits cvt_pk
__device__ inline uint32_t pkbf(float lo, float hi) {
    __bf16 l = (__bf16)lo, h = (__bf16)hi;
    uint16_t lu = __builtin_bit_cast(uint16_t, l);
    uint16_t hu = __builtin_bit_cast(uint16_t, h);
    return ((uint32_t)hu << 16) | (uint32_t)lu;
}

__device__ inline float dexp2(float x) { return __builtin_amdgcn_exp2f(x); }

// ---------------- prep: fp32 weights -> bf16.
// W_theta absorbs 1/sqrt(D) * log2(e): S' = S*log2(e), so exp(S) == exp2(S').
__global__ __launch_bounds__(256) void prep_weights(
    const float* __restrict__ wt, const float* __restrict__ wp,
    const float* __restrict__ wg, const float* __restrict__ wo,
    uint16_t* __restrict__ bwt, uint16_t* __restrict__ bwp,
    uint16_t* __restrict__ bwg, uint16_t* __restrict__ bwo)
{
    int i = blockIdx.x * 256 + threadIdx.x;   // 0..32767
    const float scale = 0.127517431f;         // log2(e)/sqrt(128)
    bwt[i] = f2bf(wt[i] * scale);
    bwp[i] = f2bf(wp[i]);
    bwg[i] = f2bf(wg[i]);
    bwo[i] = f2bf(wo[i]);
}

// ---------------- projections: z=0 qp[B][N][D], z=1 kp[B][N][D], z=2 vpT[B][D][N]
__global__ __launch_bounds__(256) void proj_kernel(
    const float* __restrict__ q, const float* __restrict__ k, const float* __restrict__ v,
    const uint16_t* __restrict__ bwt, const uint16_t* __restrict__ bwp, const uint16_t* __restrict__ bwg,
    uint16_t* __restrict__ qp, uint16_t* __restrict__ kp, uint16_t* __restrict__ vpT)
{
    const int which = blockIdx.z;
    const float* src = (which == 0) ? q : ((which == 1) ? k : v);
    const uint16_t* w = (which == 0) ? bwt : ((which == 1) ? bwp : bwg);
    const int b   = blockIdx.y;
    const int n0  = blockIdx.x * 64;
    const int wav = threadIdx.x >> 6;
    const int lane = threadIdx.x & 63;
    const int col = lane & 15;
    const int quad = lane >> 4;
    const int n = n0 + wav * 16 + col;

    const float* srcb = src + (size_t)b * C_ * N_;

    f32x4 acc[8];
#pragma unroll
    for (int mf = 0; mf < 8; ++mf) acc[mf] = (f32x4){0.f, 0.f, 0.f, 0.f};

    for (int kc = 0; kc < 8; ++kc) {
        const int cbase = kc * 32 + quad * 8;
        u16x8 bb;
#pragma unroll
        for (int j = 0; j < 8; ++j)
            bb[j] = f2bf(srcb[(size_t)(cbase + j) * N_ + n]);
        bf16x8 bfrag = __builtin_bit_cast(bf16x8, bb);
#pragma unroll
        for (int mf = 0; mf < 8; ++mf) {
            bf16x8 afrag = *(const bf16x8*)(w + (size_t)(mf * 16 + col) * C_ + cbase);
            acc[mf] = __builtin_amdgcn_mfma_f32_16x16x32_bf16(afrag, bfrag, acc[mf], 0, 0, 0);
        }
    }

    if (which < 2) {
        uint16_t* dst = (which == 0) ? qp : kp;          // [B][N][D], d contiguous
        uint16_t* base = dst + ((size_t)b * N_ + n) * D_;
#pragma unroll
        for (int mf = 0; mf < 8; ++mf) {
            u16x4 pk;
#pragma unroll
            for (int r = 0; r < 4; ++r) pk[r] = f2bf(acc[mf][r]);
            *(u16x4*)(base + mf * 16 + quad * 4) = pk;
        }
    } else {
        uint16_t* base = vpT + (size_t)b * D_ * N_;       // [B][D][N], n contiguous
#pragma unroll
        for (int mf = 0; mf < 8; ++mf)
#pragma unroll
            for (int r = 0; r < 4; ++r) {
                int d = mf * 16 + quad * 4 + r;
                base[(size_t)d * N_ + n] = f2bf(acc[mf][r]);
            }
    }
}

// ---------------- pass 1: m-tile 128, n-split x2 -> partial colsums to part[ns][b][m].
__global__ __launch_bounds__(256) void pass1_denom(
    const uint16_t* __restrict__ qp, const uint16_t* __restrict__ kp,
    float* __restrict__ part)
{
    const int b  = blockIdx.x & 7;              // XCD-local batch
    const int mt = (blockIdx.x >> 3) & 31;
    const int ns = blockIdx.x >> 8;             // n-half 0..1
    const int m0 = mt * 128;
    const int wav = threadIdx.x >> 6;
    const int lane = threadIdx.x & 63;
    const int c = lane & 15;
    const int q = lane >> 4;

    const uint16_t* qpb = qp + (size_t)b * N_ * D_;
    const uint16_t* kpb = kp + (size_t)b * N_ * D_;

    bf16x8 bfr[8][4];
#pragma unroll
    for (int mf = 0; mf < 8; ++mf)
#pragma unroll
        for (int kc = 0; kc < 4; ++kc)
            bfr[mf][kc] = *(const bf16x8*)(kpb + (size_t)(m0 + mf * 16 + c) * D_ + kc * 32 + q * 8);

    float colsum[8];
#pragma unroll
    for (int mf = 0; mf < 8; ++mf) colsum[mf] = 0.f;

    for (int it = 0; it < 32; ++it) {
        const int nbase = ns * 2048 + it * 64 + wav * 16;
        bf16x8 afr[4];
#pragma unroll
        for (int kc = 0; kc < 4; ++kc)
            afr[kc] = *(const bf16x8*)(qpb + (size_t)(nbase + c) * D_ + kc * 32 + q * 8);
#pragma unroll
        for (int mf = 0; mf < 8; ++mf) {
            f32x4 acc = (f32x4){0.f, 0.f, 0.f, 0.f};
#pragma unroll
            for (int kc = 0; kc < 4; ++kc)
                acc = __builtin_amdgcn_mfma_f32_16x16x32_bf16(afr[kc], bfr[mf][kc], acc, 0, 0, 0);
#pragma unroll
            for (int r = 0; r < 4; ++r)
                colsum[mf] += dexp2(acc[r]);
        }
    }

    __shared__ float cs[4][128];
#pragma unroll
    for (int mf = 0; mf < 8; ++mf) {
        float s = colsum[mf];
        s += __shfl_down(s, 16, 64);
        s += __shfl_down(s, 32, 64);
        if (q == 0) cs[wav][mf * 16 + c] = s;
    }
    __syncthreads();
    if (threadIdx.x < 128) {
        float s = cs[0][threadIdx.x] + cs[1][threadIdx.x] + cs[2][threadIdx.x] + cs[3][threadIdx.x];
        part[((size_t)ns * 8 + b) * N_ + m0 + threadIdx.x] = s;
    }
}

// ---------------- neglog2: l2i[b][m] = -log2(part0 + part1). Softmax denom as
// an exponent bias: P = exp2(S' + l2i[m]) == exp(S)/denom. v_log_f32 is log2.
__global__ __launch_bounds__(256) void neglog2_kernel(
    const float* __restrict__ part, float* __restrict__ l2i)
{
    int i = blockIdx.x * 256 + threadIdx.x;   // 0..32767 = (b,m)
    l2i[i] = -__builtin_amdgcn_logf(part[i] + part[32768 + i]);
}

// ---------------- pass 2 (v9): 32x32 MFMA + in-register P transpose.
// R2 counters: wall/chunk ~8.1k cy vs ~2.2k busy -> latency-exposed; LDS unit
// burst (20 reads + 8 writes/wave + DMA) + plds write->lgkm->read turnaround on
// the serial path; 5.2M conflict cy. Fix: S,PV via mfma_32x32x16; P-transpose
// via cvt_pk + permlane32_swap (VALU pipe, zero LDS): plds deleted. Softmax
// denom folded as S-accumulator init (l2i bias). K/V staging identical to R2.
// Frag reads re-derived conflict-free: K j=(2ks+h)^(m&7), V j=(2k2+h)^((d>>1)&3).
__global__ __launch_bounds__(256, 2) void pass2_attn(
    const uint16_t* __restrict__ qp, const uint16_t* __restrict__ kp,
    const uint16_t* __restrict__ vpT, const float* __restrict__ l2i,
    uint16_t* __restrict__ ob0, uint16_t* __restrict__ ob1,
    uint16_t* __restrict__ ob2, uint16_t* __restrict__ ob3)
{
    const int b   = blockIdx.x & 7;             // XCD-local batch
    const int qtr = (blockIdx.x >> 3) & 3;      // m-quarter
    const int nsb = blockIdx.x >> 5;            // 0..15
    const int wav = threadIdx.x >> 6;
    const int lane = threadIdx.x & 63;
    const int l31 = lane & 31;
    const int hl  = lane >> 5;
    const int ntile = nsb * 256 + wav * 64;     // this wave's 64 q-rows

    const uint16_t* qpb = qp + (size_t)b * N_ * D_;
    const uint16_t* kpb = kp + (size_t)b * N_ * D_;
    const uint16_t* vtb = vpT + (size_t)b * D_ * N_;
    const float* l2b = l2i + (size_t)b * N_;

    // K tile [0,4096) u16: 32 m x 16 granules (swizzled). V tile [4096,8192):
    // 128 d x 4 granules (swizzled). Double-buffered: 32 KB. No plds.
    __shared__ __align__(16) uint16_t stage[2][8192];

#define STAGE(bufidx, m0_)                                                          \
    {                                                                               \
        uint16_t* lb = &stage[bufidx][0];                                           \
        _Pragma("unroll")                                                           \
        for (int j = 0; j < 4; ++j) {                                               \
            const int fid = wav * 4 + j;                                            \
            const uint16_t* g;                                                      \
            uint16_t* ld;                                                           \
            if (fid < 8) {                                                          \
                const int P = fid * 64 + lane;                                      \
                const int mm = P >> 4, js = P & 15;                                 \
                const int jj = js ^ (mm & 7);                                       \
                g = kpb + (size_t)((m0_) + mm) * D_ + jj * 8;                       \
                ld = lb + fid * 512;                                                \
            } else {                                                                \
                const int P = (fid - 8) * 64 + lane;                                \
                const int dd = P >> 2, js = P & 3;                                  \
                const int jj = js ^ ((dd >> 1) & 3);                                \
                g = vtb + (size_t)dd * N_ + (m0_) + jj * 8;                         \
                ld = lb + 4096 + (fid - 8) * 512;                                   \
            }                                                                       \
            __builtin_amdgcn_global_load_lds(                                       \
                (const __attribute__((address_space(1))) unsigned int*)g,           \
                (__attribute__((address_space(3))) unsigned int*)ld,                \
                16, 0, 0);                                                          \
        }                                                                           \
    }

    // Q B-frags: qfr[nt][ks] = Q[ntile + nt*32 + l31][ks*16 + 8*hl .. +7]
    bf16x8 qfr[2][8];
#pragma unroll
    for (int nt = 0; nt < 2; ++nt)
#pragma unroll
        for (int ks = 0; ks < 8; ++ks)
            qfr[nt][ks] = *(const bf16x8*)(qpb + (size_t)(ntile + nt * 32 + l31) * D_ + ks * 16 + hl * 8);

    f32x16 oacc[2][4];
#pragma unroll
    for (int nt = 0; nt < 2; ++nt)
#pragma unroll
        for (int dt = 0; dt < 4; ++dt)
#pragma unroll
            for (int r = 0; r < 16; ++r) oacc[nt][dt][r] = 0.f;

    const int mstart = qtr * (N_ / 4);
    STAGE(0, mstart);
    __syncthreads();

    for (int ch = 0; ch < 32; ++ch) {
        const int m0 = mstart + ch * 32;
        const int cur = ch & 1;
        STAGE(cur ^ 1, mstart + ((ch + 1) & 31) * 32);   // prefetch (last iter: dead)

        const uint16_t* sb = &stage[cur][0];

        // denom bias: bias[g][r] = l2i[m0 + 8g + 4hl + r]; S-reg r's m is
        // (r&3) + 8*(r>>2) + 4*hl  ->  bias[r>>2][r&3]
        f32x4 bias[4];
#pragma unroll
        for (int g = 0; g < 4; ++g)
            bias[g] = *(const f32x4*)(l2b + m0 + 8 * g + 4 * hl);

        // ---- S phase: per n-tile, 8 chained 32x32x16 MFMAs (A=K rows m, B=Q cols n)
        uint32_t pf[2][2][4];   // [nt][k2][dword]: PV A-frags
        __builtin_amdgcn_s_setprio(1);
#pragma unroll
        for (int nt = 0; nt < 2; ++nt) {
            f32x16 sa;
#pragma unroll
            for (int r = 0; r < 16; ++r) sa[r] = bias[r >> 2][r & 3];
#pragma unroll
            for (int ks = 0; ks < 8; ++ks) {
                bf16x8 kf = *(const bf16x8*)(sb + l31 * 128 + ((2 * ks + hl) ^ (l31 & 7)) * 8);
                sa = __builtin_amdgcn_mfma_f32_32x32x16_bf16(kf, qfr[nt][ks], sa, 0, 0, 0);
            }
            // P = exp2(S' + bias); pack to bf16; in-register transpose via permlane
#pragma unroll
            for (int k2 = 0; k2 < 2; ++k2) {
                const int rb = k2 * 8;
                uint32_t X = pkbf(dexp2(sa[rb + 0]), dexp2(sa[rb + 1]));
                uint32_t Y = pkbf(dexp2(sa[rb + 2]), dexp2(sa[rb + 3]));
                uint32_t Z = pkbf(dexp2(sa[rb + 4]), dexp2(sa[rb + 5]));
                uint32_t W = pkbf(dexp2(sa[rb + 6]), dexp2(sa[rb + 7]));
                uiv2 xz = __builtin_amdgcn_permlane32_swap(X, Z, false, false);
                uiv2 yw = __builtin_amdgcn_permlane32_swap(Y, W, false, false);
                pf[nt][k2][0] = xz[0];
                pf[nt][k2][1] = yw[0];
                pf[nt][k2][2] = xz[1];
                pf[nt][k2][3] = yw[1];
            }
        }
        __builtin_amdgcn_s_setprio(0);

        // ---- PV phase: O[n][d] += P * V, 32x32x16, V B-frags from staged LDS
        const int vsw = (l31 >> 1) & 3;
        __builtin_amdgcn_s_setprio(1);
#pragma unroll
        for (int k2 = 0; k2 < 2; ++k2) {
#pragma unroll
            for (int dt = 0; dt < 4; ++dt) {
                bf16x8 vf = *(const bf16x8*)(sb + 4096 + (dt * 32 + l31) * 32 + ((2 * k2 + hl) ^ vsw) * 8);
                bf16x8 pa0 = __builtin_bit_cast(bf16x8, *(u32x4*)&pf[0][k2][0]);
                bf16x8 pa1 = __builtin_bit_cast(bf16x8, *(u32x4*)&pf[1][k2][0]);
                oacc[0][dt] = __builtin_amdgcn_mfma_f32_32x32x16_bf16(pa0, vf, oacc[0][dt], 0, 0, 0);
                oacc[1][dt] = __builtin_amdgcn_mfma_f32_32x32x16_bf16(pa1, vf, oacc[1][dt], 0, 0, 0);
            }
        }
        __builtin_amdgcn_s_setprio(0);

        __syncthreads();   // all waves done reading cur + own prefetch DMA drained
    }
#undef STAGE

    uint16_t* obq = (qtr == 0) ? ob0 : (qtr == 1) ? ob1 : (qtr == 2) ? ob2 : ob3;
#pragma unroll
    for (int nt = 0; nt < 2; ++nt)
#pragma unroll
        for (int dt = 0; dt < 4; ++dt)
#pragma unroll
            for (int r = 0; r < 16; ++r) {
                const int n = ntile + nt * 32 + (r & 3) + 8 * (r >> 2) + 4 * hl;
                obq[((size_t)b * N_ + n) * D_ + dt * 32 + l31] = f2bf(oacc[nt][dt][r]);
            }
}

// ---------------- pass 3: out[b][c][n] = v[b][c][n] + sum_d W_out[c][d]*(O0+O1+O2+O3)[n][d]
__global__ __launch_bounds__(256) void pass3_out(
    const uint16_t* __restrict__ ob0, const uint16_t* __restrict__ ob1,
    const uint16_t* __restrict__ ob2, const uint16_t* __restrict__ ob3,
    const uint16_t* __restrict__ bwo,
    const float* __restrict__ v, float* __restrict__ out)
{
    const int b  = blockIdx.y;
    const int n0 = blockIdx.x * 64;
    const int wav = threadIdx.x >> 6;
    const int lane = threadIdx.x & 63;
    const int col = lane & 15;
    const int quad = lane >> 4;
    const int n = n0 + wav * 16 + col;

    const float* vb = v + (size_t)b * C_ * N_;
    float* outb = out + (size_t)b * C_ * N_;
    const size_t off = ((size_t)b * N_ + n) * D_;

    bf16x8 f0[4], f1[4], f2[4], f3[4];
#pragma unroll
    for (int kc = 0; kc < 4; ++kc) {
        f0[kc] = *(const bf16x8*)(ob0 + off + kc * 32 + quad * 8);
        f1[kc] = *(const bf16x8*)(ob1 + off + kc * 32 + quad * 8);
        f2[kc] = *(const bf16x8*)(ob2 + off + kc * 32 + quad * 8);
        f3[kc] = *(const bf16x8*)(ob3 + off + kc * 32 + quad * 8);
    }

#pragma unroll
    for (int cf = 0; cf < 16; ++cf) {
        f32x4 acc = (f32x4){0.f, 0.f, 0.f, 0.f};
#pragma unroll
        for (int kc = 0; kc < 4; ++kc) {
            bf16x8 afr = *(const bf16x8*)(bwo + (size_t)(cf * 16 + col) * D_ + kc * 32 + quad * 8);
            acc = __builtin_amdgcn_mfma_f32_16x16x32_bf16(afr, f0[kc], acc, 0, 0, 0);
            acc = __builtin_amdgcn_mfma_f32_16x16x32_bf16(afr, f1[kc], acc, 0, 0, 0);
            acc = __builtin_amdgcn_mfma_f32_16x16x32_bf16(afr, f2[kc], acc, 0, 0, 0);
            acc = __builtin_amdgcn_mfma_f32_16x16x32_bf16(afr, f3[kc], acc, 0, 0, 0);
        }
#pragma unroll
        for (int r = 0; r < 4; ++r) {
            const int cc = cf * 16 + quad * 4 + r;
            const size_t idx = (size_t)cc * N_ + n;
            outb[idx] = vb[idx] + acc[r];
        }
    }
}

extern "C" void kernel_launch(void* const* d_in, const int* in_sizes, int n_in,
                              void* d_out, int out_size, void* d_ws, size_t ws_size,
                              hipStream_t stream) {
    const float* q  = (const float*)d_in[0];
    const float* k  = (const float*)d_in[1];
    const float* v  = (const float*)d_in[2];
    const float* wt = (const float*)d_in[3];
    const float* wp = (const float*)d_in[4];
    const float* wg = (const float*)d_in[5];
    const float* wo = (const float*)d_in[6];
    float* out = (float*)d_out;

    const size_t PROJ = (size_t)B_ * N_ * D_;   // 4,194,304 elems (8 MB bf16)
    uint16_t* qp  = (uint16_t*)d_ws;
    uint16_t* kp  = qp + PROJ;
    uint16_t* vpT = kp + PROJ;
    uint16_t* ob0 = vpT + PROJ;
    uint16_t* ob1 = ob0 + PROJ;
    uint16_t* ob2 = ob1 + PROJ;
    uint16_t* ob3 = ob2 + PROJ;
    uint16_t* bwt = ob3 + PROJ;
    uint16_t* bwp = bwt + (size_t)D_ * C_;
    uint16_t* bwg = bwp + (size_t)D_ * C_;
    uint16_t* bwo = bwg + (size_t)D_ * C_;
    float* part   = (float*)(bwo + (size_t)D_ * C_);   // [2][8][4096] f32, 256 KB
    float* l2i    = part + (size_t)2 * 8 * N_;         // [8][4096] f32, 128 KB
    // total ws use: 7*8MB + 4*64KB + 384KB ~= 56.63 MB

    prep_weights<<<dim3(128), 256, 0, stream>>>(wt, wp, wg, wo, bwt, bwp, bwg, bwo);
    proj_kernel<<<dim3(N_ / 64, B_, 3), 256, 0, stream>>>(q, k, v, bwt, bwp, bwg, qp, kp, vpT);
    pass1_denom<<<dim3(512), 256, 0, stream>>>(qp, kp, part);
    neglog2_kernel<<<dim3(128), 256, 0, stream>>>(part, l2i);
    pass2_attn<<<dim3(512), 256, 0, stream>>>(qp, kp, vpT, l2i, ob0, ob1, ob2, ob3);
    pass3_out<<<dim3(N_ / 64, B_), 256, 0, stream>>>(ob0, ob1, ob2, ob3, bwo, v, out);
}

// Round 4
// 365.239 us; speedup vs baseline: 1.1555x; 1.1555x over previous
//
#include <hip/hip_runtime.h>
#include <stdint.h>

#define B_ 8
#define C_ 256
#define D_ 128
#define N_ 4096

typedef __bf16 bf16x8 __attribute__((ext_vector_type(8)));
typedef uint16_t u16x8 __attribute__((ext_vector_type(8)));
typedef uint16_t u16x4 __attribute__((ext_vector_type(4)));
typedef float f32x4 __attribute__((ext_vector_type(4)));
typedef uint32_t u32x2 __attribute__((ext_vector_type(2)));

__device__ inline uint16_t f2bf(float x) {
    union { float f; uint32_t u; } v; v.f = x;
    uint32_t u = v.u;
    return (uint16_t)((u + 0x7FFFu + ((u >> 16) & 1u)) >> 16);
}

__device__ inline float bf2f(uint16_t v) {
    union { uint32_t u; float f; } x; x.u = (uint32_t)v << 16; return x.f;
}

// pack two floats -> two bf16 in one u32 (low = lo, high = hi); RNE, matches f2bf
__device__ inline uint32_t pkbf(float lo, float hi) {
    __bf16 l = (__bf16)lo, h = (__bf16)hi;
    uint16_t lu = __builtin_bit_cast(uint16_t, l);
    uint16_t hu = __builtin_bit_cast(uint16_t, h);
    return ((uint32_t)hu << 16) | (uint32_t)lu;
}

__device__ inline float dexp2(float x) { return __builtin_amdgcn_exp2f(x); }

// ---------------- prep: fp32 weights -> bf16.
// W_theta absorbs 1/sqrt(D) * log2(e): S' = S*log2(e), so exp(S) == exp2(S').
__global__ __launch_bounds__(256) void prep_weights(
    const float* __restrict__ wt, const float* __restrict__ wp,
    const float* __restrict__ wg, const float* __restrict__ wo,
    uint16_t* __restrict__ bwt, uint16_t* __restrict__ bwp,
    uint16_t* __restrict__ bwg, uint16_t* __restrict__ bwo)
{
    int i = blockIdx.x * 256 + threadIdx.x;   // 0..32767
    const float scale = 0.127517431f;         // log2(e)/sqrt(128)
    bwt[i] = f2bf(wt[i] * scale);
    bwp[i] = f2bf(wp[i]);
    bwg[i] = f2bf(wg[i]);
    bwo[i] = f2bf(wo[i]);
}

// ---------------- projections: z=0 qp[B][N][D], z=1 kp[B][N][D], z=2 vpT[B][D][N]
// R4: kc loop explicitly unrolled; afrag loads batched per kc so the 16-line
// gathers pipeline instead of serializing load->waitcnt->MFMA per mf; bfrag
// packing via cvt_pk pairs (RNE, identical rounding to f2bf).
__global__ __launch_bounds__(256) void proj_kernel(
    const float* __restrict__ q, const float* __restrict__ k, const float* __restrict__ v,
    const uint16_t* __restrict__ bwt, const uint16_t* __restrict__ bwp, const uint16_t* __restrict__ bwg,
    uint16_t* __restrict__ qp, uint16_t* __restrict__ kp, uint16_t* __restrict__ vpT)
{
    const int which = blockIdx.z;
    const float* src = (which == 0) ? q : ((which == 1) ? k : v);
    const uint16_t* w = (which == 0) ? bwt : ((which == 1) ? bwp : bwg);
    const int b   = blockIdx.y;
    const int n0  = blockIdx.x * 64;
    const int wav = threadIdx.x >> 6;
    const int lane = threadIdx.x & 63;
    const int col = lane & 15;
    const int quad = lane >> 4;
    const int n = n0 + wav * 16 + col;

    const float* srcb = src + (size_t)b * C_ * N_;

    f32x4 acc[8];
#pragma unroll
    for (int mf = 0; mf < 8; ++mf) acc[mf] = (f32x4){0.f, 0.f, 0.f, 0.f};

#pragma unroll
    for (int kc = 0; kc < 8; ++kc) {
        const int cbase = kc * 32 + quad * 8;
        bf16x8 afr[8];
#pragma unroll
        for (int mf = 0; mf < 8; ++mf)
            afr[mf] = *(const bf16x8*)(w + (size_t)(mf * 16 + col) * C_ + cbase);
        float x[8];
#pragma unroll
        for (int j = 0; j < 8; ++j)
            x[j] = srcb[(size_t)(cbase + j) * N_ + n];
        u32x2 blo = (u32x2){pkbf(x[0], x[1]), pkbf(x[2], x[3])};
        u32x2 bhi = (u32x2){pkbf(x[4], x[5]), pkbf(x[6], x[7])};
        uint32_t bw[4] = {blo[0], blo[1], bhi[0], bhi[1]};
        bf16x8 bfrag = __builtin_bit_cast(bf16x8, bw);
#pragma unroll
        for (int mf = 0; mf < 8; ++mf)
            acc[mf] = __builtin_amdgcn_mfma_f32_16x16x32_bf16(afr[mf], bfrag, acc[mf], 0, 0, 0);
    }

    if (which < 2) {
        uint16_t* dst = (which == 0) ? qp : kp;          // [B][N][D], d contiguous
        uint16_t* base = dst + ((size_t)b * N_ + n) * D_;
#pragma unroll
        for (int mf = 0; mf < 8; ++mf) {
            u32x2 pk = (u32x2){pkbf(acc[mf][0], acc[mf][1]), pkbf(acc[mf][2], acc[mf][3])};
            *(u32x2*)(base + mf * 16 + quad * 4) = pk;
        }
    } else {
        uint16_t* base = vpT + (size_t)b * D_ * N_;       // [B][D][N], n contiguous
#pragma unroll
        for (int mf = 0; mf < 8; ++mf)
#pragma unroll
            for (int r = 0; r < 4; ++r) {
                int d = mf * 16 + quad * 4 + r;
                base[(size_t)d * N_ + n] = f2bf(acc[mf][r]);
            }
    }
}

// ---------------- pass 1: m-tile 128, n-split x2 -> partial colsums to part[ns][b][m].
__global__ __launch_bounds__(256) void pass1_denom(
    const uint16_t* __restrict__ qp, const uint16_t* __restrict__ kp,
    float* __restrict__ part)
{
    const int b  = blockIdx.x & 7;              // XCD-local batch
    const int mt = (blockIdx.x >> 3) & 31;
    const int ns = blockIdx.x >> 8;             // n-half 0..1
    const int m0 = mt * 128;
    const int wav = threadIdx.x >> 6;
    const int lane = threadIdx.x & 63;
    const int c = lane & 15;
    const int q = lane >> 4;

    const uint16_t* qpb = qp + (size_t)b * N_ * D_;
    const uint16_t* kpb = kp + (size_t)b * N_ * D_;

    bf16x8 bfr[8][4];
#pragma unroll
    for (int mf = 0; mf < 8; ++mf)
#pragma unroll
        for (int kc = 0; kc < 4; ++kc)
            bfr[mf][kc] = *(const bf16x8*)(kpb + (size_t)(m0 + mf * 16 + c) * D_ + kc * 32 + q * 8);

    float colsum[8];
#pragma unroll
    for (int mf = 0; mf < 8; ++mf) colsum[mf] = 0.f;

    for (int it = 0; it < 32; ++it) {
        const int nbase = ns * 2048 + it * 64 + wav * 16;
        bf16x8 afr[4];
#pragma unroll
        for (int kc = 0; kc < 4; ++kc)
            afr[kc] = *(const bf16x8*)(qpb + (size_t)(nbase + c) * D_ + kc * 32 + q * 8);
#pragma unroll
        for (int mf = 0; mf < 8; ++mf) {
            f32x4 acc = (f32x4){0.f, 0.f, 0.f, 0.f};
#pragma unroll
            for (int kc = 0; kc < 4; ++kc)
                acc = __builtin_amdgcn_mfma_f32_16x16x32_bf16(afr[kc], bfr[mf][kc], acc, 0, 0, 0);
#pragma unroll
            for (int r = 0; r < 4; ++r)
                colsum[mf] += dexp2(acc[r]);
        }
    }

    __shared__ float cs[4][128];
#pragma unroll
    for (int mf = 0; mf < 8; ++mf) {
        float s = colsum[mf];
        s += __shfl_down(s, 16, 64);
        s += __shfl_down(s, 32, 64);
        if (q == 0) cs[wav][mf * 16 + c] = s;
    }
    __syncthreads();
    if (threadIdx.x < 128) {
        float s = cs[0][threadIdx.x] + cs[1][threadIdx.x] + cs[2][threadIdx.x] + cs[3][threadIdx.x];
        part[((size_t)ns * 8 + b) * N_ + m0 + threadIdx.x] = s;
    }
}

// ---------------- neglog2: l2i[b][m] = -log2(part0 + part1). Softmax denom as
// an exponent bias: P = exp2(S' + l2i[m]) == exp(S)/denom. v_log_f32 is log2.
__global__ __launch_bounds__(256) void neglog2_kernel(
    const float* __restrict__ part, float* __restrict__ l2i)
{
    int i = blockIdx.x * 256 + threadIdx.x;   // 0..32767 = (b,m)
    l2i[i] = -__builtin_amdgcn_logf(part[i] + part[32768 + i]);
}

// ---------------- pass 2 (v10 = R2 structure + denom-bias init).
// R3 post-mortem: 32x32 + permlane = two serial 8-deep MFMA chains + serial
// VALU tail -> MfmaUtil 16%, dur 171us. Reverted to R2 (107us known-good):
// 16x16 MFMA, swapped S (A=K), in-LDS P transpose via u32x2 writes, staged K/V
// shared by 4 waves (global_load_lds, swizzled source, linear dest).
// New vs R2: softmax denom folded as S-accumulator INIT (l2i bias) ->
// scale_vpt pass deleted. Layout check: 16x16 C/D row=(lane>>4)*4+r, so
// sacc0[r] <-> m=4q+r, sacc1[r] <-> m=16+4q+r; bias loads are f32x4 at +4q.
__global__ __launch_bounds__(256, 2) void pass2_attn(
    const uint16_t* __restrict__ qp, const uint16_t* __restrict__ kp,
    const uint16_t* __restrict__ vpT, const float* __restrict__ l2i,
    uint16_t* __restrict__ ob0, uint16_t* __restrict__ ob1,
    uint16_t* __restrict__ ob2, uint16_t* __restrict__ ob3)
{
    const int b   = blockIdx.x & 7;             // XCD-local batch
    const int qtr = (blockIdx.x >> 3) & 3;      // m-quarter
    const int nsb = blockIdx.x >> 5;            // 0..15
    const int wav = threadIdx.x >> 6;
    const int lane = threadIdx.x & 63;
    const int c = lane & 15;
    const int q = lane >> 4;
    const int ntile = nsb * 256 + wav * 64;     // this wave's 64 q-rows

    const uint16_t* qpb = qp + (size_t)b * N_ * D_;
    const uint16_t* kpb = kp + (size_t)b * N_ * D_;
    const uint16_t* vtb = vpT + (size_t)b * D_ * N_;
    const float* l2b = l2i + (size_t)b * N_;

    // K tile [0,4096) u16: 32 m x 128 d, granule-swizzled. V tile [4096,8192):
    // 128 d x 32 m. Double-buffered: 32 KB.
    __shared__ __align__(16) uint16_t stage[2][8192];
    // wave-private P transpose buffer, row stride 72 u16 = 144 B
    __shared__ __align__(16) uint16_t plds[4][4][16][72];   // 36,864 B

#define STAGE(bufidx, m0_)                                                          \
    {                                                                               \
        uint16_t* lb = &stage[bufidx][0];                                           \
        _Pragma("unroll")                                                           \
        for (int j = 0; j < 4; ++j) {                                               \
            const int fid = wav * 4 + j;                                            \
            const uint16_t* g;                                                      \
            uint16_t* ld;                                                           \
            if (fid < 8) {                                                          \
                const int P = fid * 64 + lane;                                      \
                const int mm = P >> 4, js = P & 15;                                 \
                const int jj = js ^ (mm & 7);                                       \
                g = kpb + (size_t)((m0_) + mm) * D_ + jj * 8;                       \
                ld = lb + fid * 512;                                                \
            } else {                                                                \
                const int P = (fid - 8) * 64 + lane;                                \
                const int dd = P >> 2, js = P & 3;                                  \
                const int jj = js ^ ((dd >> 1) & 3);                                \
                g = vtb + (size_t)dd * N_ + (m0_) + jj * 8;                         \
                ld = lb + 4096 + (fid - 8) * 512;                                   \
            }                                                                       \
            __builtin_amdgcn_global_load_lds(                                       \
                (const __attribute__((address_space(1))) unsigned int*)g,           \
                (__attribute__((address_space(3))) unsigned int*)ld,                \
                16, 0, 0);                                                          \
        }                                                                           \
    }

    bf16x8 qfr[4][4];
#pragma unroll
    for (int nf = 0; nf < 4; ++nf)
#pragma unroll
        for (int kc = 0; kc < 4; ++kc)
            qfr[nf][kc] = *(const bf16x8*)(qpb + (size_t)(ntile + nf * 16 + c) * D_ + kc * 32 + q * 8);

    f32x4 oacc[4][8];
#pragma unroll
    for (int nf = 0; nf < 4; ++nf)
#pragma unroll
        for (int df = 0; df < 8; ++df) oacc[nf][df] = (f32x4){0.f, 0.f, 0.f, 0.f};

    const int mstart = qtr * (N_ / 4);
    STAGE(0, mstart);
    __syncthreads();

    for (int ch = 0; ch < 32; ++ch) {
        const int m0 = mstart + ch * 32;
        const int cur = ch & 1;
        STAGE(cur ^ 1, mstart + ((ch + 1) & 31) * 32);   // prefetch (last iter: dead)

        const uint16_t* sb = &stage[cur][0];

        // denom bias: sacc0[r] <-> m = m0+4q+r, sacc1[r] <-> m = m0+16+4q+r
        const f32x4 bias0 = *(const f32x4*)(l2b + m0 + 4 * q);
        const f32x4 bias1 = *(const f32x4*)(l2b + m0 + 16 + 4 * q);

        // K fragments from LDS (swizzled): lane (q,c), m = mf*16+c, j = kc*4+q
        bf16x8 kf[2][4];
#pragma unroll
        for (int mf = 0; mf < 2; ++mf)
#pragma unroll
            for (int kc = 0; kc < 4; ++kc) {
                const int js = (kc * 4 + q) ^ (c & 7);   // m&7 == c&7
                kf[mf][kc] = *(const bf16x8*)(sb + (mf * 16 + c) * 128 + js * 8);
            }

        // S phase (swapped: A=K rows m, B=Q rows n) + exp2 + pack to plds
        __builtin_amdgcn_s_setprio(1);
#pragma unroll
        for (int nf = 0; nf < 4; ++nf) {
            f32x4 s0 = bias0;
            f32x4 s1 = bias1;
#pragma unroll
            for (int kc = 0; kc < 4; ++kc)
                s0 = __builtin_amdgcn_mfma_f32_16x16x32_bf16(kf[0][kc], qfr[nf][kc], s0, 0, 0, 0);
#pragma unroll
            for (int kc = 0; kc < 4; ++kc)
                s1 = __builtin_amdgcn_mfma_f32_16x16x32_bf16(kf[1][kc], qfr[nf][kc], s1, 0, 0, 0);
            // lane (q,c): s0[r] = S[m0+4q+r][ntile+nf*16+c] + bias; s1[r] = +16 m
            uint32_t p00 = pkbf(dexp2(s0[0]), dexp2(s0[1]));
            uint32_t p01 = pkbf(dexp2(s0[2]), dexp2(s0[3]));
            uint32_t p10 = pkbf(dexp2(s1[0]), dexp2(s1[1]));
            uint32_t p11 = pkbf(dexp2(s1[2]), dexp2(s1[3]));
            uint16_t* row = &plds[wav][nf][c][0];
            *(u32x2*)(row + 4 * q)      = (u32x2){p00, p01};   // m-local 4q..4q+3
            *(u32x2*)(row + 16 + 4 * q) = (u32x2){p10, p11};   // m-local 16+4q..+3
        }
        __builtin_amdgcn_s_setprio(0);

        // V fragments from LDS (swizzled): lane (q,c), d = df*16+c, j = q
        const int vjs = q ^ ((c >> 1) & 3);    // (d>>1)&3 == (c>>1)&3
        bf16x8 vf[8];
#pragma unroll
        for (int df = 0; df < 8; ++df)
            vf[df] = *(const bf16x8*)(sb + 4096 + (df * 16 + c) * 32 + vjs * 8);

        // P A-fragments: lane (q,c) reads n=c row, k = m-local 8q..8q+7
        bf16x8 pf[4];
#pragma unroll
        for (int nf = 0; nf < 4; ++nf)
            pf[nf] = *(const bf16x8*)(&plds[wav][nf][c][8 * q]);

        __builtin_amdgcn_s_setprio(1);
#pragma unroll
        for (int nf = 0; nf < 4; ++nf)
#pragma unroll
            for (int df = 0; df < 8; ++df)
                oacc[nf][df] = __builtin_amdgcn_mfma_f32_16x16x32_bf16(pf[nf], vf[df], oacc[nf][df], 0, 0, 0);
        __builtin_amdgcn_s_setprio(0);

        __syncthreads();   // all waves done reading cur + own prefetch DMA drained
    }
#undef STAGE

    uint16_t* obq = (qtr == 0) ? ob0 : (qtr == 1) ? ob1 : (qtr == 2) ? ob2 : ob3;
#pragma unroll
    for (int nf = 0; nf < 4; ++nf) {
        uint16_t* ob = obq + ((size_t)b * N_ + ntile + nf * 16) * D_;   // [B][N][D]
#pragma unroll
        for (int df = 0; df < 8; ++df)
#pragma unroll
            for (int r = 0; r < 4; ++r)
                ob[(size_t)(q * 4 + r) * D_ + df * 16 + c] = f2bf(oacc[nf][df][r]);
    }
}

// ---------------- pass 3: out[b][c][n] = v[b][c][n] + sum_d W_out[c][d]*(O0+O1+O2+O3)[n][d]
__global__ __launch_bounds__(256) void pass3_out(
    const uint16_t* __restrict__ ob0, const uint16_t* __restrict__ ob1,
    const uint16_t* __restrict__ ob2, const uint16_t* __restrict__ ob3,
    const uint16_t* __restrict__ bwo,
    const float* __restrict__ v, float* __restrict__ out)
{
    const int b  = blockIdx.y;
    const int n0 = blockIdx.x * 64;
    const int wav = threadIdx.x >> 6;
    const int lane = threadIdx.x & 63;
    const int col = lane & 15;
    const int quad = lane >> 4;
    const int n = n0 + wav * 16 + col;

    const float* vb = v + (size_t)b * C_ * N_;
    float* outb = out + (size_t)b * C_ * N_;
    const size_t off = ((size_t)b * N_ + n) * D_;

    bf16x8 f0[4], f1[4], f2[4], f3[4];
#pragma unroll
    for (int kc = 0; kc < 4; ++kc) {
        f0[kc] = *(const bf16x8*)(ob0 + off + kc * 32 + quad * 8);
        f1[kc] = *(const bf16x8*)(ob1 + off + kc * 32 + quad * 8);
        f2[kc] = *(const bf16x8*)(ob2 + off + kc * 32 + quad * 8);
        f3[kc] = *(const bf16x8*)(ob3 + off + kc * 32 + quad * 8);
    }

#pragma unroll
    for (int cf = 0; cf < 16; ++cf) {
        f32x4 acc = (f32x4){0.f, 0.f, 0.f, 0.f};
#pragma unroll
        for (int kc = 0; kc < 4; ++kc) {
            bf16x8 afr = *(const bf16x8*)(bwo + (size_t)(cf * 16 + col) * D_ + kc * 32 + quad * 8);
            acc = __builtin_amdgcn_mfma_f32_16x16x32_bf16(afr, f0[kc], acc, 0, 0, 0);
            acc = __builtin_amdgcn_mfma_f32_16x16x32_bf16(afr, f1[kc], acc, 0, 0, 0);
            acc = __builtin_amdgcn_mfma_f32_16x16x32_bf16(afr, f2[kc], acc, 0, 0, 0);
            acc = __builtin_amdgcn_mfma_f32_16x16x32_bf16(afr, f3[kc], acc, 0, 0, 0);
        }
#pragma unroll
        for (int r = 0; r < 4; ++r) {
            const int cc = cf * 16 + quad * 4 + r;
            const size_t idx = (size_t)cc * N_ + n;
            outb[idx] = vb[idx] + acc[r];
        }
    }
}

extern "C" void kernel_launch(void* const* d_in, const int* in_sizes, int n_in,
                              void* d_out, int out_size, void* d_ws, size_t ws_size,
                              hipStream_t stream) {
    const float* q  = (const float*)d_in[0];
    const float* k  = (const float*)d_in[1];
    const float* v  = (const float*)d_in[2];
    const float* wt = (const float*)d_in[3];
    const float* wp = (const float*)d_in[4];
    const float* wg = (const float*)d_in[5];
    const float* wo = (const float*)d_in[6];
    float* out = (float*)d_out;

    const size_t PROJ = (size_t)B_ * N_ * D_;   // 4,194,304 elems (8 MB bf16)
    uint16_t* qp  = (uint16_t*)d_ws;
    uint16_t* kp  = qp + PROJ;
    uint16_t* vpT = kp + PROJ;
    uint16_t* ob0 = vpT + PROJ;
    uint16_t* ob1 = ob0 + PROJ;
    uint16_t* ob2 = ob1 + PROJ;
    uint16_t* ob3 = ob2 + PROJ;
    uint16_t* bwt = ob3 + PROJ;
    uint16_t* bwp = bwt + (size_t)D_ * C_;
    uint16_t* bwg = bwp + (size_t)D_ * C_;
    uint16_t* bwo = bwg + (size_t)D_ * C_;
    float* part   = (float*)(bwo + (size_t)D_ * C_);   // [2][8][4096] f32, 256 KB
    float* l2i    = part + (size_t)2 * 8 * N_;         // [8][4096] f32, 128 KB
    // total ws use: 7*8MB + 4*64KB + 384KB ~= 56.63 MB

    prep_weights<<<dim3(128), 256, 0, stream>>>(wt, wp, wg, wo, bwt, bwp, bwg, bwo);
    proj_kernel<<<dim3(N_ / 64, B_, 3), 256, 0, stream>>>(q, k, v, bwt, bwp, bwg, qp, kp, vpT);
    pass1_denom<<<dim3(512), 256, 0, stream>>>(qp, kp, part);
    neglog2_kernel<<<dim3(128), 256, 0, stream>>>(part, l2i);
    pass2_attn<<<dim3(512), 256, 0, stream>>>(qp, kp, vpT, l2i, ob0, ob1, ob2, ob3);
    pass3_out<<<dim3(N_ / 64, B_), 256, 0, stream>>>(ob0, ob1, ob2, ob3, bwo, v, out);
}